// Round 2
// baseline (681.058 us; speedup 1.0000x reference)
//
#include <hip/hip_runtime.h>
#include <hip/hip_bf16.h>

#define B_   32
#define T_   4096
#define D_   1024
#define E_   128
#define K_   16
#define KEV_ 8
#define DE_  (D_ + E_)      // 1152
#define MAXTIME_ 512

typedef __attribute__((ext_vector_type(8))) short short8;     // 8 x bf16 (4 VGPRs)
typedef __attribute__((ext_vector_type(4))) short short4v;
typedef __attribute__((ext_vector_type(4))) float floatx4;    // MFMA acc

// fp32 -> bf16 (round-to-nearest-even), result as raw short bits
__device__ __forceinline__ short bf16rn(float f) {
    unsigned u = __builtin_bit_cast(unsigned, f);
    u += 0x7FFFu + ((u >> 16) & 1u);
    return (short)(u >> 16);
}

// ---------------------------------------------------------------------------
// K1: per-batch top-8 (ties -> lower index) + merge with uniform grid,
// sorted-unique, truncate to K. Writes chosen/valid ws + valid/times outputs.
// ---------------------------------------------------------------------------
__global__ __launch_bounds__(256) void topk_merge(
    const float* __restrict__ scores,
    int* __restrict__ chosen_ws, int* __restrict__ valid_ws,
    float* __restrict__ out_valid, float* __restrict__ out_times)
{
    __shared__ float sc[T_];
    __shared__ float rv[256];
    __shared__ int   ri[256];
    __shared__ int   found[KEV_];
    const int b = blockIdx.x, tid = threadIdx.x;

    for (int i = tid; i < T_; i += 256)
        sc[i] = scores[b * T_ + i];
    __syncthreads();

    for (int r = 0; r < KEV_; ++r) {
        float bv = -INFINITY; int bi = T_;
        for (int i = tid; i < T_; i += 256) {
            float v = sc[i];
            if (v > bv) { bv = v; bi = i; }   // strict >: keeps lowest index on ties
        }
        rv[tid] = bv; ri[tid] = bi;
        __syncthreads();
        for (int s = 128; s > 0; s >>= 1) {
            if (tid < s) {
                float ov = rv[tid + s]; int oi = ri[tid + s];
                if (ov > rv[tid] || (ov == rv[tid] && oi < ri[tid])) {
                    rv[tid] = ov; ri[tid] = oi;
                }
            }
            __syncthreads();
        }
        if (tid == 0) { found[r] = ri[0]; sc[ri[0]] = -INFINITY; }
        __syncthreads();
    }

    if (tid == 0) {
        int arr[KEV_ + K_];
        for (int i = 0; i < KEV_; ++i) arr[i] = found[i];
        for (int j = 0; j < K_; ++j)  arr[KEV_ + j] = j * 273;   // linspace(0,4095,16) exact
        for (int i = 1; i < KEV_ + K_; ++i) {                    // insertion sort (24)
            int v = arr[i], j = i - 1;
            while (j >= 0 && arr[j] > v) { arr[j + 1] = arr[j]; --j; }
            arr[j + 1] = v;
        }
        int u[KEV_ + K_]; int m = 0;
        for (int i = 0; i < KEV_ + K_; ++i)
            if (i == 0 || arr[i] != arr[i - 1]) u[m++] = arr[i];
        int n = (m < K_) ? m : K_;
        for (int k = 0; k < K_; ++k) {
            int c  = (k < m) ? u[k] : 0;      // ref compaction buffer zero-filled
            int vf = (k < n) ? 1 : 0;
            chosen_ws[b * K_ + k] = c;
            valid_ws [b * K_ + k] = vf;
            out_valid[b * K_ + k] = (float)vf;
            out_times[b * K_ + k] = (float)(vf ? c : 0);
        }
    }
}

// ---------------------------------------------------------------------------
// K2: one block per (b,k) row. holder_out = hl * vf (fp32 exact copy),
// softmax(hl) fp32, raw = [bf16(g) | bf16(softmax)] into ws.
// ---------------------------------------------------------------------------
__global__ __launch_bounds__(128) void build_raw(
    const float* __restrict__ state,
    const float* __restrict__ hlog,
    const int* __restrict__ chosen_ws,
    const int* __restrict__ valid_ws,
    short* __restrict__ rawA,
    float* __restrict__ out_holder)
{
    const int row = blockIdx.x;           // b*K + k
    const int tid = threadIdx.x;          // 0..127
    const int b   = row >> 4;
    const int t   = chosen_ws[row];
    const int vf  = valid_ws[row];

    __shared__ float sh[E_];
    __shared__ float se[E_];

    float x = hlog[((size_t)b * T_ + t) * E_ + tid];
    sh[tid] = x;
    out_holder[(size_t)row * E_ + tid] = vf ? x : 0.0f;
    __syncthreads();

    float mx = -INFINITY;
    for (int i = 0; i < E_; ++i) mx = fmaxf(mx, sh[i]);
    float e = expf(x - mx);
    se[tid] = e;
    __syncthreads();
    float sum = 0.0f;
    for (int i = 0; i < E_; ++i) sum += se[i];
    rawA[(size_t)row * DE_ + D_ + tid] = bf16rn(e / sum);

    // g: fp32 state row -> bf16, vectorized float4 -> short4
    const float4* gsrc = (const float4*)(state + ((size_t)b * T_ + t) * D_);
    short4v*      gdst = (short4v*)(rawA + (size_t)row * DE_);
#pragma unroll
    for (int i = tid; i < D_ / 4; i += 128) {
        float4 v = gsrc[i];
        short4v s;
        s[0] = bf16rn(v.x); s[1] = bf16rn(v.y);
        s[2] = bf16rn(v.z); s[3] = bf16rn(v.w);
        gdst[i] = s;
    }
}

// ---------------------------------------------------------------------------
// K3: MFMA GEMM [512,1152](bf16 ws) x W[1024,1152]^T (fp32, cvt in-register)
// fused epilogue: +bias, +time_table[min(chosen,511)], *valid, fp32 store.
// One wave = 16 rows x 64 cols. 512 waves.
// ---------------------------------------------------------------------------
__global__ __launch_bounds__(256) void gemm_ep(
    const short* __restrict__ rawA,
    const float* __restrict__ W,
    const float* __restrict__ bias,
    const float* __restrict__ ttab,
    const int* __restrict__ chosen_ws,
    const int* __restrict__ valid_ws,
    float* __restrict__ out_entries)
{
    const int tid  = threadIdx.x;
    const int lane = tid & 63;
    const int wid  = (blockIdx.x << 2) + (tid >> 6);  // 0..511
    const int r    = wid & 31;                        // row tile (16 rows)
    const int cg   = wid >> 5;                        // col group (64 cols)

    const int fl = lane & 15;    // m for A-frag, n for B-frag
    const int kq = lane >> 4;    // k-quad

    floatx4 acc0 = {0,0,0,0}, acc1 = {0,0,0,0}, acc2 = {0,0,0,0}, acc3 = {0,0,0,0};

    const short8* Arow = (const short8*)(rawA + (size_t)(r * 16 + fl) * DE_);
    const float4* B0 = (const float4*)(W + (size_t)(cg * 64 +  0 + fl) * DE_);
    const float4* B1 = (const float4*)(W + (size_t)(cg * 64 + 16 + fl) * DE_);
    const float4* B2 = (const float4*)(W + (size_t)(cg * 64 + 32 + fl) * DE_);
    const float4* B3 = (const float4*)(W + (size_t)(cg * 64 + 48 + fl) * DE_);

#pragma unroll 2
    for (int k0 = 0; k0 < DE_; k0 += 32) {
        const int oa = (k0 >> 3) + kq;       // short8 units
        const int ob = (k0 >> 2) + (kq << 1);// float4 units
        short8 a = Arow[oa];
        float4 x0 = B0[ob], y0 = B0[ob + 1];
        float4 x1 = B1[ob], y1 = B1[ob + 1];
        float4 x2 = B2[ob], y2 = B2[ob + 1];
        float4 x3 = B3[ob], y3 = B3[ob + 1];
        short8 b0, b1, b2, b3;
        b0[0]=bf16rn(x0.x); b0[1]=bf16rn(x0.y); b0[2]=bf16rn(x0.z); b0[3]=bf16rn(x0.w);
        b0[4]=bf16rn(y0.x); b0[5]=bf16rn(y0.y); b0[6]=bf16rn(y0.z); b0[7]=bf16rn(y0.w);
        b1[0]=bf16rn(x1.x); b1[1]=bf16rn(x1.y); b1[2]=bf16rn(x1.z); b1[3]=bf16rn(x1.w);
        b1[4]=bf16rn(y1.x); b1[5]=bf16rn(y1.y); b1[6]=bf16rn(y1.z); b1[7]=bf16rn(y1.w);
        b2[0]=bf16rn(x2.x); b2[1]=bf16rn(x2.y); b2[2]=bf16rn(x2.z); b2[3]=bf16rn(x2.w);
        b2[4]=bf16rn(y2.x); b2[5]=bf16rn(y2.y); b2[6]=bf16rn(y2.z); b2[7]=bf16rn(y2.w);
        b3[0]=bf16rn(x3.x); b3[1]=bf16rn(x3.y); b3[2]=bf16rn(x3.z); b3[3]=bf16rn(x3.w);
        b3[4]=bf16rn(y3.x); b3[5]=bf16rn(y3.y); b3[6]=bf16rn(y3.z); b3[7]=bf16rn(y3.w);
        acc0 = __builtin_amdgcn_mfma_f32_16x16x32_bf16(a, b0, acc0, 0, 0, 0);
        acc1 = __builtin_amdgcn_mfma_f32_16x16x32_bf16(a, b1, acc1, 0, 0, 0);
        acc2 = __builtin_amdgcn_mfma_f32_16x16x32_bf16(a, b2, acc2, 0, 0, 0);
        acc3 = __builtin_amdgcn_mfma_f32_16x16x32_bf16(a, b3, acc3, 0, 0, 0);
    }

    // C/D layout: col = lane&15, row = (lane>>4)*4 + reg
    const int mbase = r * 16 + kq * 4;
    int   tclip[4]; float vfm[4];
#pragma unroll
    for (int i = 0; i < 4; ++i) {
        int m = mbase + i;
        int c = chosen_ws[m];
        tclip[i] = (c < MAXTIME_ - 1) ? c : (MAXTIME_ - 1);
        vfm[i]   = (float)valid_ws[m];
    }

    floatx4 accs[4] = {acc0, acc1, acc2, acc3};
#pragma unroll
    for (int ct = 0; ct < 4; ++ct) {
        const int o  = cg * 64 + ct * 16 + fl;
        const float bo = bias[o];
#pragma unroll
        for (int reg = 0; reg < 4; ++reg) {
            const int m  = mbase + reg;
            const float te = ttab[(size_t)tclip[reg] * D_ + o];
            out_entries[(size_t)m * D_ + o] = (accs[ct][reg] + bo + te) * vfm[reg];
        }
    }
}

// ---------------------------------------------------------------------------
extern "C" void kernel_launch(void* const* d_in, const int* in_sizes, int n_in,
                              void* d_out, int out_size, void* d_ws, size_t ws_size,
                              hipStream_t stream)
{
    const float* state = (const float*)d_in[0]; // [32,4096,1024]
    const float* hlog  = (const float*)d_in[1]; // [32,4096,128]
    const float* esc   = (const float*)d_in[2]; // [32,4096]
    const float* Wm    = (const float*)d_in[3]; // [1024,1152]
    const float* bias  = (const float*)d_in[4]; // [1024]
    const float* ttab  = (const float*)d_in[5]; // [512,1024]

    float* out         = (float*)d_out;
    float* out_entries = out;                  // 32*16*1024 = 524288
    float* out_valid   = out + 524288;         // 512
    float* out_times   = out + 524800;         // 512
    float* out_holder  = out + 525312;         // 65536

    char* ws = (char*)d_ws;
    short* rawA    = (short*)ws;                        // 512*1152*2 = 1179648 B
    int* chosen_ws = (int*)(ws + 1179648);              // 512 ints
    int* valid_ws  = (int*)(ws + 1179648 + 2048);       // 512 ints

    topk_merge<<<B_, 256, 0, stream>>>(esc, chosen_ws, valid_ws, out_valid, out_times);
    build_raw<<<B_ * K_, 128, 0, stream>>>(state, hlog, chosen_ws, valid_ws, rawA, out_holder);
    gemm_ep<<<128, 256, 0, stream>>>(rawA, Wm, bias, ttab, chosen_ws, valid_ws, out_entries);
}